// Round 8
// baseline (89.766 us; speedup 1.0000x reference)
//
#include <hip/hip_runtime.h>

#define H 4096
#define W 4096
#define R 4              // rows per block (smaller -> 4096 blocks, better CU refill)
#define TC 4             // cols per thread
#define TPB 256
#define STRIP (TPB*TC)   // 1024 cols per block
#define NSTRIP (W/STRIP) // 4
#define NBAND (H/R)      // 1024
#define NBLK (NSTRIP*NBAND) // 4096 partials
#define LN2 0.69314718055994531f

// Rolling 3-row window, advancing-pointer addressing (1 add/ptr/row; halos fold
// into load immediates at -4B/+16B). Latency hidden by TLP: 64-VGPR cap -> 8 waves/SIMD.
template<bool INTERIOR>
__device__ __forceinline__ float band_loss(const float* __restrict__ sp0,
                                           const float* __restrict__ op0,
                                           int r0, bool lv, bool rv) {
  float sa[TC], sb[TC], sc[TC];
  float oa[TC], ob[TC], oc[TC];
  float sLa, sLb, sLc, sRa, sRb, sRc;
  float oLa, oLb, oLc, oRa, oRb, oRc;

  const float* sp = sp0 - W;   // row r0-1
  const float* op = op0 - W;

  auto loadrow = [&](bool valid, float* sv, float* ov,
                     float& sl, float& sr, float& ol, float& orr) {
    if (valid) {
      const float4 fs = *reinterpret_cast<const float4*>(sp);
      const float4 fo = *reinterpret_cast<const float4*>(op);
      sv[0] = fs.x; sv[1] = fs.y; sv[2] = fs.z; sv[3] = fs.w;
      ov[0] = fo.x; ov[1] = fo.y; ov[2] = fo.z; ov[3] = fo.w;
      sl  = lv ? sp[-1] : 0.f;    // same vaddr, imm offset -4
      ol  = lv ? op[-1] : 0.f;
      sr  = rv ? sp[TC] : 0.f;    // imm offset +16
      orr = rv ? op[TC] : 0.f;
    } else {
      sv[0] = sv[1] = sv[2] = sv[3] = 0.f;
      ov[0] = ov[1] = ov[2] = ov[3] = 0.f;
      sl = sr = ol = orr = 0.f;
    }
  };

  loadrow(INTERIOR || (r0 - 1 >= 0), sa, oa, sLa, sRa, oLa, oRa);
  sp += W; op += W;
  loadrow(true, sb, ob, sLb, sRb, oLb, oRb);

  float acc = 0.f;

  #pragma unroll
  for (int i = 0; i < R; ++i) {
    sp += W; op += W;
    loadrow(INTERIOR || (r0 + i + 1 < H), sc, oc, sLc, sRc, oLc, oRc);

    float cs[TC], co[TC];
    #pragma unroll
    for (int k = 0; k < TC; ++k) {
      cs[k] = sa[k] + sb[k] + sc[k];
      co[k] = oa[k] + ob[k] + oc[k];
    }
    const float csL = sLa + sLb + sLc;
    const float csR = sRa + sRb + sRc;
    const float coL = oLa + oLb + oLc;
    const float coR = oRa + oRb + oRc;

    #pragma unroll
    for (int k = 0; k < TC; ++k) {
      const float cl  = (k == 0)    ? csL : cs[k-1];
      const float cr  = (k == TC-1) ? csR : cs[k+1];
      const float nsS = cl + cs[k] + cr - sb[k];     // 8-neighbor sum of seg
      const float col = (k == 0)    ? coL : co[k-1];
      const float cor = (k == TC-1) ? coR : co[k+1];
      const float nsO = col + co[k] + cor - ob[k];   // 8-neighbor sum of out
      const float w1 = 9.f - nsS;                    // sig_seg_1
      const float m0 = 1.f + nsO;                    // sig_out_0
      const float s = sb[k], o = ob[k];
      // log2 units; one LN2 scale at the very end (reduce kernel)
      acc += w1 * s * __log2f(o + 1e-5f) + m0 * (1.f - s) * __log2f(1.00001f - o);
    }

    #pragma unroll
    for (int k = 0; k < TC; ++k) {
      sa[k] = sb[k]; sb[k] = sc[k];
      oa[k] = ob[k]; ob[k] = oc[k];
    }
    sLa = sLb; sLb = sLc;  sRa = sRb; sRb = sRc;
    oLa = oLb; oLb = oLc;  oRa = oRb; oRb = oRc;
  }
  return acc;
}

__global__ __launch_bounds__(TPB, 8)   // pin VGPR<=64 -> 8 waves/SIMD allowed
void wbce_kernel(const float* __restrict__ outp, const float* __restrict__ segp,
                 float* __restrict__ partial) {
  // Bijective XCD-chunk swizzle (NBLK % 8 == 0): each XCD owns a contiguous
  // slab of row-bands so band-halo rows are re-read from its own L2.
  const int p = blockIdx.x;
  const int logical = (p & 7) * (NBLK / 8) + (p >> 3);
  const int strip = logical & (NSTRIP - 1);
  const int band  = logical >> 2;            // NSTRIP == 4
  const int t     = threadIdx.x;
  const int r0    = band * R;
  const int c0    = strip * STRIP + t * TC;
  const bool lv   = (c0 > 0);
  const bool rv   = (c0 + TC < W);

  const float* sp0 = segp + (size_t)r0 * W + c0;
  const float* op0 = outp + (size_t)r0 * W + c0;

  float acc;
  if (band > 0 && band < NBAND - 1) acc = band_loss<true >(sp0, op0, r0, lv, rv);
  else                              acc = band_loss<false>(sp0, op0, r0, lv, rv);

  // wave reduce (64 lanes)
  #pragma unroll
  for (int off = 32; off > 0; off >>= 1) acc += __shfl_down(acc, off, 64);

  __shared__ float wsum[TPB / 64];
  if ((t & 63) == 0) wsum[t >> 6] = acc;
  __syncthreads();
  if (t == 0)
    partial[band * NSTRIP + strip] = wsum[0] + wsum[1] + wsum[2] + wsum[3];
}

__global__ __launch_bounds__(TPB)
void reduce_kernel(const float* __restrict__ partial, float* __restrict__ out) {
  const int t = threadIdx.x;
  float a = 0.f;
  #pragma unroll
  for (int i = 0; i < NBLK / (TPB * 4); ++i) {   // 4096 floats = 4 float4/thread
    const float4 v = reinterpret_cast<const float4*>(partial)[t + i * TPB];
    a += v.x + v.y + v.z + v.w;
  }
  #pragma unroll
  for (int off = 32; off > 0; off >>= 1) a += __shfl_down(a, off, 64);
  __shared__ float ws[TPB / 64];
  if ((t & 63) == 0) ws[t >> 6] = a;
  __syncthreads();
  if (t == 0)
    out[0] = (ws[0] + ws[1] + ws[2] + ws[3]) * (-LN2 / ((float)H * (float)W));
}

extern "C" void kernel_launch(void* const* d_in, const int* in_sizes, int n_in,
                              void* d_out, int out_size, void* d_ws, size_t ws_size,
                              hipStream_t stream) {
  const float* outp = (const float*)d_in[0];  // out_image
  const float* segp = (const float*)d_in[1];  // segment_image
  float* part = (float*)d_ws;                 // 4096 floats of scratch
  float* o = (float*)d_out;
  wbce_kernel<<<dim3(NBLK), TPB, 0, stream>>>(outp, segp, part);
  reduce_kernel<<<1, TPB, 0, stream>>>(part, o);
}

// Round 9
// 49.154 us; speedup vs baseline: 1.8262x; 1.8262x over previous
//
#include <hip/hip_runtime.h>

#define H 4096
#define W 4096
#define R 16             // rows per block: 18/16 = 1.125x read redundancy
#define TC 4             // cols per thread
#define TPB 256
#define STRIP (TPB*TC)   // 1024 cols per block
#define NSTRIP (W/STRIP) // 4
#define NBAND (H/R)      // 256
#define NBLK (NSTRIP*NBAND) // 1024 blocks = exactly 4/CU, one scheduling round
#define LN2 0.69314718055994531f

// Rolling 3-row window, advancing pointers, shfl-based halo columns:
// 2 float4 loads/row for all lanes; only lanes 0/63 add exec-masked edge scalars.
template<bool INTERIOR>
__device__ __forceinline__ float band_loss(const float* __restrict__ sp0,
                                           const float* __restrict__ op0,
                                           int r0, bool eL, bool eR, int lane) {
  float sa[TC], sb[TC], sc[TC];
  float oa[TC], ob[TC], oc[TC];
  float sLa, sLb, sLc, oLa, oLb, oLc;   // live only on lane 0
  float sRa, sRb, sRc, oRa, oRb, oRc;   // live only on lane 63

  const float* sp = sp0 - W;   // row r0-1
  const float* op = op0 - W;

  auto loadrow = [&](bool valid, float* sv, float* ov,
                     float& sl, float& ol, float& sr, float& orr) {
    if (valid) {
      const float4 fs = *reinterpret_cast<const float4*>(sp);
      const float4 fo = *reinterpret_cast<const float4*>(op);
      sv[0] = fs.x; sv[1] = fs.y; sv[2] = fs.z; sv[3] = fs.w;
      ov[0] = fo.x; ov[1] = fo.y; ov[2] = fo.z; ov[3] = fo.w;
      sl  = eL ? sp[-1] : 0.f;    // exec-masked: lane 0 only
      ol  = eL ? op[-1] : 0.f;
      sr  = eR ? sp[TC] : 0.f;    // lane 63 only
      orr = eR ? op[TC] : 0.f;
    } else {
      sv[0] = sv[1] = sv[2] = sv[3] = 0.f;
      ov[0] = ov[1] = ov[2] = ov[3] = 0.f;
      sl = ol = sr = orr = 0.f;
    }
  };

  loadrow(INTERIOR || (r0 - 1 >= 0), sa, oa, sLa, oLa, sRa, oRa);
  sp += W; op += W;
  loadrow(true, sb, ob, sLb, oLb, sRb, oRb);

  float acc = 0.f;

  #pragma unroll
  for (int i = 0; i < R; ++i) {
    sp += W; op += W;
    loadrow(INTERIOR || (r0 + i + 1 < H), sc, oc, sLc, oLc, sRc, oRc);

    float cs[TC], co[TC];
    #pragma unroll
    for (int k = 0; k < TC; ++k) {
      cs[k] = sa[k] + sb[k] + sc[k];
      co[k] = oa[k] + ob[k] + oc[k];
    }

    // halo column sums from neighbor lanes; lanes 0/63 use their edge loads
    float csL = __shfl_up(cs[TC-1], 1, 64);
    float coL = __shfl_up(co[TC-1], 1, 64);
    float csR = __shfl_down(cs[0], 1, 64);
    float coR = __shfl_down(co[0], 1, 64);
    if (lane == 0)  { csL = sLa + sLb + sLc; coL = oLa + oLb + oLc; }
    if (lane == 63) { csR = sRa + sRb + sRc; coR = oRa + oRb + oRc; }

    #pragma unroll
    for (int k = 0; k < TC; ++k) {
      const float cl  = (k == 0)    ? csL : cs[k-1];
      const float cr  = (k == TC-1) ? csR : cs[k+1];
      const float nsS = cl + cs[k] + cr - sb[k];     // 8-neighbor sum of seg
      const float col = (k == 0)    ? coL : co[k-1];
      const float cor = (k == TC-1) ? coR : co[k+1];
      const float nsO = col + co[k] + cor - ob[k];   // 8-neighbor sum of out
      const float w1 = 9.f - nsS;                    // sig_seg_1
      const float m0 = 1.f + nsO;                    // sig_out_0
      const float s = sb[k], o = ob[k];
      // log2 units; single LN2 scale in the reduce kernel
      acc += w1 * s * __log2f(o + 1e-5f) + m0 * (1.f - s) * __log2f(1.00001f - o);
    }

    #pragma unroll
    for (int k = 0; k < TC; ++k) {
      sa[k] = sb[k]; sb[k] = sc[k];
      oa[k] = ob[k]; ob[k] = oc[k];
    }
    sLa = sLb; sLb = sLc;  oLa = oLb; oLb = oLc;
    sRa = sRb; sRb = sRc;  oRa = oRb; oRb = oRc;
  }
  return acc;
}

__global__ __launch_bounds__(TPB)   // NO min-waves hint (R8 lesson: it forces spills)
void wbce_kernel(const float* __restrict__ outp, const float* __restrict__ segp,
                 float* __restrict__ partial) {
  // Bijective XCD-chunk swizzle (NBLK % 8 == 0): each XCD owns a contiguous
  // slab of row-bands so band-halo rows are re-read from its own L2.
  const int p = blockIdx.x;
  const int logical = (p & 7) * (NBLK / 8) + (p >> 3);
  const int strip = logical & (NSTRIP - 1);
  const int band  = logical >> 2;            // NSTRIP == 4
  const int t     = threadIdx.x;
  const int r0    = band * R;
  const int c0    = strip * STRIP + t * TC;
  const int lane  = t & 63;
  const bool eL   = (lane == 0)  && (c0 > 0);
  const bool eR   = (lane == 63) && (c0 + TC < W);

  const float* sp0 = segp + (size_t)r0 * W + c0;
  const float* op0 = outp + (size_t)r0 * W + c0;

  float acc;
  if (band > 0 && band < NBAND - 1) acc = band_loss<true >(sp0, op0, r0, eL, eR, lane);
  else                              acc = band_loss<false>(sp0, op0, r0, eL, eR, lane);

  // wave reduce (64 lanes)
  #pragma unroll
  for (int off = 32; off > 0; off >>= 1) acc += __shfl_down(acc, off, 64);

  __shared__ float wsum[TPB / 64];
  if ((t & 63) == 0) wsum[t >> 6] = acc;
  __syncthreads();
  if (t == 0)
    partial[band * NSTRIP + strip] = wsum[0] + wsum[1] + wsum[2] + wsum[3];
}

__global__ __launch_bounds__(TPB)
void reduce_kernel(const float* __restrict__ partial, float* __restrict__ out) {
  const int t = threadIdx.x;
  const float4 v = reinterpret_cast<const float4*>(partial)[t];  // 1024 floats
  float a = v.x + v.y + v.z + v.w;
  #pragma unroll
  for (int off = 32; off > 0; off >>= 1) a += __shfl_down(a, off, 64);
  __shared__ float ws[TPB / 64];
  if ((t & 63) == 0) ws[t >> 6] = a;
  __syncthreads();
  if (t == 0)
    out[0] = (ws[0] + ws[1] + ws[2] + ws[3]) * (-LN2 / ((float)H * (float)W));
}

extern "C" void kernel_launch(void* const* d_in, const int* in_sizes, int n_in,
                              void* d_out, int out_size, void* d_ws, size_t ws_size,
                              hipStream_t stream) {
  const float* outp = (const float*)d_in[0];  // out_image
  const float* segp = (const float*)d_in[1];  // segment_image
  float* part = (float*)d_ws;                 // 1024 floats of scratch
  float* o = (float*)d_out;
  wbce_kernel<<<dim3(NBLK), TPB, 0, stream>>>(outp, segp, part);
  reduce_kernel<<<1, TPB, 0, stream>>>(part, o);
}

// Round 10
// 38.139 us; speedup vs baseline: 2.3536x; 1.2888x over previous
//
#include <hip/hip_runtime.h>

#define H 4096
#define W 4096
#define R 8              // rows per block (round-7 best-known geometry)
#define TC 4             // cols per thread
#define TPB 256
#define STRIP (TPB*TC)   // 1024 cols per block
#define NSTRIP (W/STRIP) // 4
#define NBAND (H/R)      // 512
#define NBLK (NSTRIP*NBAND) // 2048 partials
#define LN2 0.69314718055994531f

// Round-7 structure (rolling 3-row window, advancing pointers) with ONE change:
// halo columns come from __shfl of neighbor lanes' column sums instead of 4
// per-lane scalar gathers per row. VMEM/row: 6 -> 2 (+ rare exec-masked edges).
template<bool INTERIOR>
__device__ __forceinline__ float band_loss(const float* __restrict__ sp0,
                                           const float* __restrict__ op0,
                                           int r0, bool eL, bool eR, int lane) {
  float sa[TC], sb[TC], sc[TC];
  float oa[TC], ob[TC], oc[TC];
  float sLa, sLb, sLc, oLa, oLb, oLc;   // live only on lane 0 (wave-left edge)
  float sRa, sRb, sRc, oRa, oRb, oRc;   // live only on lane 63 (wave-right edge)

  const float* sp = sp0 - W;   // row r0-1
  const float* op = op0 - W;

  auto loadrow = [&](bool valid, float* sv, float* ov,
                     float& sl, float& ol, float& sr, float& orr) {
    if (valid) {
      const float4 fs = *reinterpret_cast<const float4*>(sp);
      const float4 fo = *reinterpret_cast<const float4*>(op);
      sv[0] = fs.x; sv[1] = fs.y; sv[2] = fs.z; sv[3] = fs.w;
      ov[0] = fo.x; ov[1] = fo.y; ov[2] = fo.z; ov[3] = fo.w;
      sl  = eL ? sp[-1] : 0.f;    // exec-masked: lane 0 only, imm offset -4
      ol  = eL ? op[-1] : 0.f;
      sr  = eR ? sp[TC] : 0.f;    // lane 63 only, imm offset +16
      orr = eR ? op[TC] : 0.f;
    } else {
      sv[0] = sv[1] = sv[2] = sv[3] = 0.f;
      ov[0] = ov[1] = ov[2] = ov[3] = 0.f;
      sl = ol = sr = orr = 0.f;
    }
  };

  loadrow(INTERIOR || (r0 - 1 >= 0), sa, oa, sLa, oLa, sRa, oRa);
  sp += W; op += W;
  loadrow(true, sb, ob, sLb, oLb, sRb, oRb);

  float acc = 0.f;

  #pragma unroll
  for (int i = 0; i < R; ++i) {
    sp += W; op += W;
    loadrow(INTERIOR || (r0 + i + 1 < H), sc, oc, sLc, oLc, sRc, oRc);

    float cs[TC], co[TC];
    #pragma unroll
    for (int k = 0; k < TC; ++k) {
      cs[k] = sa[k] + sb[k] + sc[k];
      co[k] = oa[k] + ob[k] + oc[k];
    }

    // halo column sums via cross-lane shuffle; wave-edge lanes use edge loads
    float csL = __shfl_up(cs[TC-1], 1, 64);
    float coL = __shfl_up(co[TC-1], 1, 64);
    float csR = __shfl_down(cs[0], 1, 64);
    float coR = __shfl_down(co[0], 1, 64);
    if (lane == 0)  { csL = sLa + sLb + sLc; coL = oLa + oLb + oLc; }
    if (lane == 63) { csR = sRa + sRb + sRc; coR = oRa + oRb + oRc; }

    #pragma unroll
    for (int k = 0; k < TC; ++k) {
      const float cl  = (k == 0)    ? csL : cs[k-1];
      const float cr  = (k == TC-1) ? csR : cs[k+1];
      const float nsS = cl + cs[k] + cr - sb[k];     // 8-neighbor sum of seg
      const float col = (k == 0)    ? coL : co[k-1];
      const float cor = (k == TC-1) ? coR : co[k+1];
      const float nsO = col + co[k] + cor - ob[k];   // 8-neighbor sum of out
      const float w1 = 9.f - nsS;                    // sig_seg_1
      const float m0 = 1.f + nsO;                    // sig_out_0
      const float s = sb[k], o = ob[k];
      // log2 units; single LN2 scale in the reduce kernel
      acc += w1 * s * __log2f(o + 1e-5f) + m0 * (1.f - s) * __log2f(1.00001f - o);
    }

    #pragma unroll
    for (int k = 0; k < TC; ++k) {
      sa[k] = sb[k]; sb[k] = sc[k];
      oa[k] = ob[k]; ob[k] = oc[k];
    }
    sLa = sLb; sLb = sLc;  oLa = oLb; oLb = oLc;
    sRa = sRb; sRb = sRc;  oRa = oRb; oRb = oRc;
  }
  return acc;
}

__global__ __launch_bounds__(TPB)   // no min-waves hint (R8 lesson: forces spills)
void wbce_kernel(const float* __restrict__ outp, const float* __restrict__ segp,
                 float* __restrict__ partial) {
  const int t     = threadIdx.x;
  const int strip = blockIdx.x;
  const int band  = blockIdx.y;
  const int r0    = band * R;
  const int c0    = strip * STRIP + t * TC;
  const int lane  = t & 63;
  const bool eL   = (lane == 0)  && (c0 > 0);
  const bool eR   = (lane == 63) && (c0 + TC < W);

  const float* sp0 = segp + (size_t)r0 * W + c0;
  const float* op0 = outp + (size_t)r0 * W + c0;

  float acc;
  if (band > 0 && band < NBAND - 1) acc = band_loss<true >(sp0, op0, r0, eL, eR, lane);
  else                              acc = band_loss<false>(sp0, op0, r0, eL, eR, lane);

  // wave reduce (64 lanes)
  #pragma unroll
  for (int off = 32; off > 0; off >>= 1) acc += __shfl_down(acc, off, 64);

  __shared__ float wsum[TPB / 64];
  if ((t & 63) == 0) wsum[t >> 6] = acc;
  __syncthreads();
  if (t == 0)
    partial[band * NSTRIP + strip] = wsum[0] + wsum[1] + wsum[2] + wsum[3];
}

__global__ __launch_bounds__(TPB)
void reduce_kernel(const float* __restrict__ partial, float* __restrict__ out) {
  const int t = threadIdx.x;
  float a = 0.f;
  #pragma unroll
  for (int i = 0; i < NBLK / (TPB * 4); ++i) {   // 2048 floats = 2 float4/thread
    const float4 v = reinterpret_cast<const float4*>(partial)[t + i * TPB];
    a += v.x + v.y + v.z + v.w;
  }
  #pragma unroll
  for (int off = 32; off > 0; off >>= 1) a += __shfl_down(a, off, 64);
  __shared__ float ws[TPB / 64];
  if ((t & 63) == 0) ws[t >> 6] = a;
  __syncthreads();
  if (t == 0)
    out[0] = (ws[0] + ws[1] + ws[2] + ws[3]) * (-LN2 / ((float)H * (float)W));
}

extern "C" void kernel_launch(void* const* d_in, const int* in_sizes, int n_in,
                              void* d_out, int out_size, void* d_ws, size_t ws_size,
                              hipStream_t stream) {
  const float* outp = (const float*)d_in[0];  // out_image
  const float* segp = (const float*)d_in[1];  // segment_image
  float* part = (float*)d_ws;                 // 2048 floats of scratch
  float* o = (float*)d_out;
  wbce_kernel<<<dim3(NSTRIP, NBAND), TPB, 0, stream>>>(outp, segp, part);
  reduce_kernel<<<1, TPB, 0, stream>>>(part, o);
}

// Round 11
// 35.602 us; speedup vs baseline: 2.5214x; 1.0713x over previous
//
#include <hip/hip_runtime.h>

#define H 4096
#define W 4096
#define R 8               // rows per band
#define TC 4              // cols per thread
#define TPB 256
#define STRIP (TPB*TC)    // 1024 cols per block
#define NSTRIP (W/STRIP)  // 4
#define NBAND (H/R)       // 512
#define NPART (NSTRIP*NBAND*4)  // 8192 per-wave partials
#define NS 3              // LDS slots per wave per input
#define LN2 0.69314718055994531f

__device__ __forceinline__ void dma16(const float* g, float* l) {
  // async global->LDS, 16B/lane, zero VGPR landing buffers
  __builtin_amdgcn_global_load_lds((const __attribute__((address_space(1))) void*)g,
                                   (__attribute__((address_space(3))) void*)l, 16, 0, 0);
}

// ---- edge-band fallback: R7's proven register rolling window ----
__device__ float band_loss_edge(const float* __restrict__ sp0,
                                const float* __restrict__ op0,
                                int r0, bool lv, bool rv) {
  float sa[TC], sb[TC], sc[TC];
  float oa[TC], ob[TC], oc[TC];
  float sLa, sLb, sLc, sRa, sRb, sRc;
  float oLa, oLb, oLc, oRa, oRb, oRc;
  const float* sp = sp0 - W;
  const float* op = op0 - W;
  auto loadrow = [&](bool valid, float* sv, float* ov,
                     float& sl, float& sr, float& ol, float& orr) {
    if (valid) {
      const float4 fs = *reinterpret_cast<const float4*>(sp);
      const float4 fo = *reinterpret_cast<const float4*>(op);
      sv[0] = fs.x; sv[1] = fs.y; sv[2] = fs.z; sv[3] = fs.w;
      ov[0] = fo.x; ov[1] = fo.y; ov[2] = fo.z; ov[3] = fo.w;
      sl  = lv ? sp[-1] : 0.f;  ol  = lv ? op[-1] : 0.f;
      sr  = rv ? sp[TC] : 0.f;  orr = rv ? op[TC] : 0.f;
    } else {
      sv[0]=sv[1]=sv[2]=sv[3]=0.f; ov[0]=ov[1]=ov[2]=ov[3]=0.f;
      sl = sr = ol = orr = 0.f;
    }
  };
  loadrow(r0 - 1 >= 0, sa, oa, sLa, sRa, oLa, oRa);
  sp += W; op += W;
  loadrow(true, sb, ob, sLb, sRb, oLb, oRb);
  float acc = 0.f;
  #pragma unroll
  for (int i = 0; i < R; ++i) {
    sp += W; op += W;
    loadrow(r0 + i + 1 < H, sc, oc, sLc, sRc, oLc, oRc);
    float cs[TC], co[TC];
    #pragma unroll
    for (int k = 0; k < TC; ++k) {
      cs[k] = sa[k] + sb[k] + sc[k];
      co[k] = oa[k] + ob[k] + oc[k];
    }
    const float csL = sLa + sLb + sLc, csR = sRa + sRb + sRc;
    const float coL = oLa + oLb + oLc, coR = oRa + oRb + oRc;
    #pragma unroll
    for (int k = 0; k < TC; ++k) {
      const float cl  = (k == 0)    ? csL : cs[k-1];
      const float cr  = (k == TC-1) ? csR : cs[k+1];
      const float nsS = cl + cs[k] + cr - sb[k];
      const float col = (k == 0)    ? coL : co[k-1];
      const float cor = (k == TC-1) ? coR : co[k+1];
      const float nsO = col + co[k] + cor - ob[k];
      const float w1 = 9.f - nsS;
      const float m0 = 1.f + nsO;
      const float s = sb[k], o = ob[k];
      acc += w1 * s * __log2f(o + 1e-5f) + m0 * (1.f - s) * __log2f(1.00001f - o);
    }
    #pragma unroll
    for (int k = 0; k < TC; ++k) {
      sa[k] = sb[k]; sb[k] = sc[k];
      oa[k] = ob[k]; ob[k] = oc[k];
    }
    sLa = sLb; sLb = sLc;  sRa = sRb; sRb = sRc;
    oLa = oLb; oLb = oLc;  oRa = oRb; oRb = oRc;
  }
  return acc;
}

__global__ __launch_bounds__(TPB)
void wbce_kernel(const float* __restrict__ outp, const float* __restrict__ segp,
                 float* __restrict__ partial) {
  const int t     = threadIdx.x;
  const int strip = blockIdx.x;
  const int band  = blockIdx.y;
  const int w     = t >> 6;        // wave id
  const int lane  = t & 63;
  const int r0    = band * R;
  const int wc0   = strip * STRIP + w * 256;   // wave's 256-col slice base
  const int c0    = wc0 + lane * TC;

  // wave-private LDS ring: [wave][slot][input][256 cols]; no barriers needed
  __shared__ __align__(16) float lds[4][NS][2][256];   // 24 KB

  float acc = 0.f;

  if (band > 0 && band < NBAND - 1) {
    float* slab = &lds[w][0][0][0];            // wave-uniform base

    // --- prologue: wave-edge halo columns into lane-0/63 registers ---
    float eS[R+2], eO[R+2];
    #pragma unroll
    for (int j = 0; j < R+2; ++j) { eS[j] = 0.f; eO[j] = 0.f; }
    const bool eAct = (lane == 0 && wc0 > 0) || (lane == 63 && wc0 + 256 < W);
    const int  ecol = (lane == 0) ? (wc0 - 1) : (wc0 + 256);
    if (eAct) {                                 // exec-masked to 2 lanes
      const float* es = segp + (size_t)(r0 - 1) * W + ecol;
      const float* eo = outp + (size_t)(r0 - 1) * W + ecol;
      #pragma unroll
      for (int j = 0; j < R+2; ++j) {
        eS[j] = es[(size_t)j * W];
        eO[j] = eo[(size_t)j * W];
      }
    }

    // --- prologue: rows j=0,1 into registers; DMA rows j=2,3 into LDS ---
    const float* sg = segp + (size_t)(r0 - 1) * W + c0;
    const float* og = outp + (size_t)(r0 - 1) * W + c0;
    float4 s0 = *reinterpret_cast<const float4*>(sg);
    float4 o0 = *reinterpret_cast<const float4*>(og);
    float4 s1 = *reinterpret_cast<const float4*>(sg + W);
    float4 o1 = *reinterpret_cast<const float4*>(og + W);

    const float* sd = sg + 2 * (size_t)W;       // DMA cursor: row j=2
    const float* od = og + 2 * (size_t)W;
    dma16(sd,     slab + (2 % NS) * 512);       // seg row2 -> slot2
    dma16(od,     slab + (2 % NS) * 512 + 256);
    dma16(sd + W, slab + (3 % NS) * 512);       // seg row3 -> slot0
    dma16(od + W, slab + (3 % NS) * 512 + 256);
    sd += 2 * (size_t)W; od += 2 * (size_t)W;   // cursor: row j=4

    #pragma unroll
    for (int i = 0; i < R; ++i) {
      // issue row j=i+4 (2 pairs stay in flight; counted vmcnt, never 0 mid-loop)
      if (i + 4 <= R + 1) {
        const int sl = (i + 4) % NS;
        dma16(sd, slab + sl * 512);
        dma16(od, slab + sl * 512 + 256);
        sd += W; od += W;
      }
      if (i < R - 2)       asm volatile("s_waitcnt vmcnt(4)" ::: "memory");
      else if (i == R - 2) asm volatile("s_waitcnt vmcnt(2)" ::: "memory");
      else                 asm volatile("s_waitcnt vmcnt(0)" ::: "memory");

      // fresh row j=i+2 from LDS (ds_read_b128, conflict-free stride-16)
      const int sl2 = (i + 2) % NS;
      const float4 s2 = *reinterpret_cast<const float4*>(slab + sl2 * 512 +       lane * 4);
      const float4 o2 = *reinterpret_cast<const float4*>(slab + sl2 * 512 + 256 + lane * 4);

      float cs[TC], co[TC];
      cs[0] = s0.x + s1.x + s2.x;  cs[1] = s0.y + s1.y + s2.y;
      cs[2] = s0.z + s1.z + s2.z;  cs[3] = s0.w + s1.w + s2.w;
      co[0] = o0.x + o1.x + o2.x;  co[1] = o0.y + o1.y + o2.y;
      co[2] = o0.z + o1.z + o2.z;  co[3] = o0.w + o1.w + o2.w;

      const float esum_s = eS[i] + eS[i+1] + eS[i+2];
      const float esum_o = eO[i] + eO[i+1] + eO[i+2];
      float csL = __shfl_up(cs[3], 1, 64);   if (lane == 0)  csL = esum_s;
      float coL = __shfl_up(co[3], 1, 64);   if (lane == 0)  coL = esum_o;
      float csR = __shfl_down(cs[0], 1, 64); if (lane == 63) csR = esum_s;
      float coR = __shfl_down(co[0], 1, 64); if (lane == 63) coR = esum_o;

      const float sb[TC] = { s1.x, s1.y, s1.z, s1.w };
      const float ob[TC] = { o1.x, o1.y, o1.z, o1.w };
      #pragma unroll
      for (int k = 0; k < TC; ++k) {
        const float cl  = (k == 0)    ? csL : cs[k-1];
        const float cr  = (k == TC-1) ? csR : cs[k+1];
        const float nsS = cl + cs[k] + cr - sb[k];     // 8-neighbor sum (seg)
        const float col = (k == 0)    ? coL : co[k-1];
        const float cor = (k == TC-1) ? coR : co[k+1];
        const float nsO = col + co[k] + cor - ob[k];   // 8-neighbor sum (out)
        const float w1 = 9.f - nsS;                    // sig_seg_1
        const float m0 = 1.f + nsO;                    // sig_out_0
        const float s = sb[k], o = ob[k];
        acc += w1 * s * __log2f(o + 1e-5f) + m0 * (1.f - s) * __log2f(1.00001f - o);
      }

      s0 = s1; s1 = s2;  o0 = o1; o1 = o2;   // renamed, not moved (full unroll)
    }
  } else {
    const bool lv = (c0 > 0);
    const bool rv = (c0 + TC < W);
    acc = band_loss_edge(segp + (size_t)r0 * W + c0,
                         outp + (size_t)r0 * W + c0, r0, lv, rv);
  }

  // wave reduce; one partial per wave, no atomics, no block barrier
  #pragma unroll
  for (int off = 32; off > 0; off >>= 1) acc += __shfl_down(acc, off, 64);
  if (lane == 0)
    partial[((band * NSTRIP + strip) << 2) + w] = acc;
}

__global__ __launch_bounds__(TPB)
void reduce_kernel(const float* __restrict__ partial, float* __restrict__ out) {
  const int t = threadIdx.x;
  float a = 0.f;
  #pragma unroll
  for (int i = 0; i < NPART / (TPB * 4); ++i) {   // 8192 floats = 8 float4/thread
    const float4 v = reinterpret_cast<const float4*>(partial)[t + i * TPB];
    a += v.x + v.y + v.z + v.w;
  }
  #pragma unroll
  for (int off = 32; off > 0; off >>= 1) a += __shfl_down(a, off, 64);
  __shared__ float ws[TPB / 64];
  if ((t & 63) == 0) ws[t >> 6] = a;
  __syncthreads();
  if (t == 0)
    out[0] = (ws[0] + ws[1] + ws[2] + ws[3]) * (-LN2 / ((float)H * (float)W));
}

extern "C" void kernel_launch(void* const* d_in, const int* in_sizes, int n_in,
                              void* d_out, int out_size, void* d_ws, size_t ws_size,
                              hipStream_t stream) {
  const float* outp = (const float*)d_in[0];  // out_image
  const float* segp = (const float*)d_in[1];  // segment_image
  float* part = (float*)d_ws;                 // 8192 floats of scratch
  float* o = (float*)d_out;
  wbce_kernel<<<dim3(NSTRIP, NBAND), TPB, 0, stream>>>(outp, segp, part);
  reduce_kernel<<<1, TPB, 0, stream>>>(part, o);
}

// Round 12
// 31.577 us; speedup vs baseline: 2.8428x; 1.1275x over previous
//
#include <hip/hip_runtime.h>

#define H 4096
#define W 4096
#define R 8              // rows per block (round-7 best-known geometry)
#define TC 4             // cols per thread
#define TPB 256
#define STRIP (TPB*TC)   // 1024 cols per block
#define NSTRIP (W/STRIP) // 4
#define NBAND (H/R)      // 512
#define NBLK (NSTRIP*NBAND) // 2048
#define BANDS_PER_XCD (NBAND/8) // 64
#define LN2 0.69314718055994531f

// R7 kernel (32.6 us best) with exactly ONE change: XCD-chunked block swizzle,
// band-contiguous within a strip, so vertically-adjacent bands (which re-read
// each other's halo rows) run consecutively on the SAME XCD -> halo re-reads
// hit that XCD's L2 instead of going back to L3/HBM.
template<bool INTERIOR>
__device__ __forceinline__ float band_loss(const float* __restrict__ sp0,
                                           const float* __restrict__ op0,
                                           int r0, bool lv, bool rv) {
  float sa[TC], sb[TC], sc[TC];
  float oa[TC], ob[TC], oc[TC];
  float sLa, sLb, sLc, sRa, sRb, sRc;
  float oLa, oLb, oLc, oRa, oRb, oRc;

  const float* sp = sp0 - W;   // row r0-1
  const float* op = op0 - W;

  auto loadrow = [&](bool valid, float* sv, float* ov,
                     float& sl, float& sr, float& ol, float& orr) {
    if (valid) {
      const float4 fs = *reinterpret_cast<const float4*>(sp);
      const float4 fo = *reinterpret_cast<const float4*>(op);
      sv[0] = fs.x; sv[1] = fs.y; sv[2] = fs.z; sv[3] = fs.w;
      ov[0] = fo.x; ov[1] = fo.y; ov[2] = fo.z; ov[3] = fo.w;
      sl  = lv ? sp[-1] : 0.f;    // same vaddr, imm offset -4
      ol  = lv ? op[-1] : 0.f;
      sr  = rv ? sp[TC] : 0.f;    // imm offset +16
      orr = rv ? op[TC] : 0.f;
    } else {
      sv[0] = sv[1] = sv[2] = sv[3] = 0.f;
      ov[0] = ov[1] = ov[2] = ov[3] = 0.f;
      sl = sr = ol = orr = 0.f;
    }
  };

  loadrow(INTERIOR || (r0 - 1 >= 0), sa, oa, sLa, sRa, oLa, oRa);
  sp += W; op += W;
  loadrow(true, sb, ob, sLb, sRb, oLb, oRb);

  float acc = 0.f;

  #pragma unroll
  for (int i = 0; i < R; ++i) {
    sp += W; op += W;
    loadrow(INTERIOR || (r0 + i + 1 < H), sc, oc, sLc, sRc, oLc, oRc);

    float cs[TC], co[TC];
    #pragma unroll
    for (int k = 0; k < TC; ++k) {
      cs[k] = sa[k] + sb[k] + sc[k];
      co[k] = oa[k] + ob[k] + oc[k];
    }
    const float csL = sLa + sLb + sLc;
    const float csR = sRa + sRb + sRc;
    const float coL = oLa + oLb + oLc;
    const float coR = oRa + oRb + oRc;

    #pragma unroll
    for (int k = 0; k < TC; ++k) {
      const float cl  = (k == 0)    ? csL : cs[k-1];
      const float cr  = (k == TC-1) ? csR : cs[k+1];
      const float nsS = cl + cs[k] + cr - sb[k];     // 8-neighbor sum of seg
      const float col = (k == 0)    ? coL : co[k-1];
      const float cor = (k == TC-1) ? coR : co[k+1];
      const float nsO = col + co[k] + cor - ob[k];   // 8-neighbor sum of out
      const float w1 = 9.f - nsS;                    // sig_seg_1
      const float m0 = 1.f + nsO;                    // sig_out_0
      const float s = sb[k], o = ob[k];
      // log2 units; one LN2 scale at the very end (reduce kernel)
      acc += w1 * s * __log2f(o + 1e-5f) + m0 * (1.f - s) * __log2f(1.00001f - o);
    }

    #pragma unroll
    for (int k = 0; k < TC; ++k) {
      sa[k] = sb[k]; sb[k] = sc[k];
      oa[k] = ob[k]; ob[k] = oc[k];
    }
    sLa = sLb; sLb = sLc;  sRa = sRb; sRb = sRc;
    oLa = oLb; oLb = oLc;  oRa = oRb; oRb = oRc;
  }
  return acc;
}

__global__ __launch_bounds__(TPB)
void wbce_kernel(const float* __restrict__ outp, const float* __restrict__ segp,
                 float* __restrict__ partial) {
  // Bijective XCD swizzle (2048 % 8 == 0). Chunk = 256 blocks on one XCD
  // covering bands [xcd*64, xcd*64+64) for all 4 strips; WITHIN the chunk,
  // consecutive blocks are consecutive BANDS of the same strip, so the 2
  // shared halo rows of band b are still in this XCD's L2 when band b+1 runs.
  const int p    = blockIdx.x;
  const int xcd  = p & 7;
  const int idx  = p >> 3;                   // 0..255 within chunk
  const int strip = idx >> 6;                // 0..3 (64 bands per strip-run)
  const int band  = xcd * BANDS_PER_XCD + (idx & (BANDS_PER_XCD - 1));

  const int t     = threadIdx.x;
  const int r0    = band * R;
  const int c0    = strip * STRIP + t * TC;
  const bool lv   = (c0 > 0);
  const bool rv   = (c0 + TC < W);

  const float* sp0 = segp + (size_t)r0 * W + c0;
  const float* op0 = outp + (size_t)r0 * W + c0;

  float acc;
  if (band > 0 && band < NBAND - 1) acc = band_loss<true >(sp0, op0, r0, lv, rv);
  else                              acc = band_loss<false>(sp0, op0, r0, lv, rv);

  // wave reduce (64 lanes)
  #pragma unroll
  for (int off = 32; off > 0; off >>= 1) acc += __shfl_down(acc, off, 64);

  __shared__ float wsum[TPB / 64];
  if ((t & 63) == 0) wsum[t >> 6] = acc;
  __syncthreads();
  if (t == 0)
    partial[band * NSTRIP + strip] = wsum[0] + wsum[1] + wsum[2] + wsum[3];
}

__global__ __launch_bounds__(TPB)
void reduce_kernel(const float* __restrict__ partial, float* __restrict__ out) {
  const int t = threadIdx.x;
  float a = 0.f;
  #pragma unroll
  for (int i = 0; i < NBLK / (TPB * 4); ++i) {   // 2048 floats = 2 float4/thread
    const float4 v = reinterpret_cast<const float4*>(partial)[t + i * TPB];
    a += v.x + v.y + v.z + v.w;
  }
  #pragma unroll
  for (int off = 32; off > 0; off >>= 1) a += __shfl_down(a, off, 64);
  __shared__ float ws[TPB / 64];
  if ((t & 63) == 0) ws[t >> 6] = a;
  __syncthreads();
  if (t == 0)
    out[0] = (ws[0] + ws[1] + ws[2] + ws[3]) * (-LN2 / ((float)H * (float)W));
}

extern "C" void kernel_launch(void* const* d_in, const int* in_sizes, int n_in,
                              void* d_out, int out_size, void* d_ws, size_t ws_size,
                              hipStream_t stream) {
  const float* outp = (const float*)d_in[0];  // out_image
  const float* segp = (const float*)d_in[1];  // segment_image
  float* part = (float*)d_ws;                 // 2048 floats of scratch
  float* o = (float*)d_out;
  wbce_kernel<<<dim3(NBLK), TPB, 0, stream>>>(outp, segp, part);
  reduce_kernel<<<1, TPB, 0, stream>>>(part, o);
}